// Round 12
// baseline (257.406 us; speedup 1.0000x reference)
//
#include <hip/hip_runtime.h>
#include <hip/hip_bf16.h>

#define VOCABN 50000
#define BN 128
#define CN 5
#define HN 50
#define LN 32
#define DN 300
#define DP 320     // padded K
#define KNN 20

typedef __bf16    bf16x8 __attribute__((ext_vector_type(8)));
typedef float     f32x4  __attribute__((ext_vector_type(4)));
typedef ushort    u16x8  __attribute__((ext_vector_type(8)));

#if __has_builtin(__builtin_amdgcn_exp2f)
#define FEXP2 __builtin_amdgcn_exp2f
#else
#define FEXP2 exp2f
#endif
#if __has_builtin(__builtin_amdgcn_logf)
#define FLOG2 __builtin_amdgcn_logf
#else
#define FLOG2 log2f
#endif

#define LOG2E 1.4426950408889634f
#define LN2F  0.6931471805599453f

// ---------------- kernel 1: normalize vocab -> bf16 table, wave-per-row (R11-proven) ----------------
__global__ __launch_bounds__(256) void knorm_embed2(const float* __restrict__ emb,
                                                    ushort* __restrict__ tabo) {
    const int t    = threadIdx.x;
    const int lane = t & 63;
    const int w    = t >> 6;
    const int v    = blockIdx.x * 4 + w;          // grid 12500 x 4 waves
    const float* row = emb + (size_t)v * DN;
    const float4* r4 = (const float4*)row;        // rows are 1200B -> 16B aligned

    float4 x = r4[lane];
    float ss = x.x * x.x + x.y * x.y + x.z * x.z + x.w * x.w;
    if (lane < 11) {
        float4 y = r4[64 + lane];
        ss += y.x * y.x + y.y * y.y + y.z * y.z + y.w * y.w;
    }
    #pragma unroll
    for (int off = 32; off; off >>= 1) ss += __shfl_xor(ss, off);
    const float scale = 1.0f / fmaxf(sqrtf(ss), 1e-8f);

    if (lane < 40) {
        u16x8 u;
        #pragma unroll
        for (int j = 0; j < 8; ++j) {
            int e = lane * 8 + j;
            float f = (e < DN) ? row[e] * scale : 0.f;
            __hip_bfloat16 h = __float2bfloat16(f);
            u[j] = *(ushort*)&h;
        }
        *(u16x8*)(tabo + (size_t)v * DP + lane * 8) = u;
    }
}

// A buffer: [32 rows][40 chunks of 16B] = 640B rows; XOR swizzle within 8-chunk octets.
// bank of chunk = 4*((ch^(row&7))&7) -> rows spread over 8 bank-groups, 2-way max (free).
__device__ inline bf16x8 ldA(const ushort* A, int row, int ch) {
    int pos = (ch & ~7) | ((ch & 7) ^ (row & 7));
    return *(const bf16x8*)((const char*)A + row * 640 + pos * 16);
}

// ---------------- kernel 2: fused GEMM + pooling, wave-independent (no K-loop barriers) ----------------
// Block = (b,c), 5 waves; wave w owns h = w*10 .. w*10+9. A staged once in LDS;
// B per-lane direct-gathered with 1-step prefetch; acc[2][2]=16 regs; pool per h.
__global__ __launch_bounds__(320) void knrm_fused4(const int* __restrict__ cand,
                                                   const int* __restrict__ clik,
                                                   const ushort* __restrict__ tab,
                                                   const float* __restrict__ ltr_w,
                                                   float* __restrict__ score) {
    __shared__ __align__(16) ushort Abuf[32 * 320];     // 20 KB, full-K A for this c
    __shared__ __align__(16) float  simbuf[5][16 * 33]; // 10.6 KB, wave-private
    __shared__ int tokB[1600];                          // 6.4 KB
    __shared__ int tokA[32];

    const int t    = threadIdx.x;
    const int lane = t & 63;
    const int w    = t >> 6;
    // T1: bijective XCD swizzle (grid 640 = 8 x 80); same-b blocks co-XCD
    const int bid  = (blockIdx.x & 7) * 80 + (blockIdx.x >> 3);
    const int b    = bid / CN;
    const int c    = bid % CN;

    if (t < 32) tokA[t] = cand[b * (CN * LN) + c * LN + t];
    #pragma unroll
    for (int it = 0; it < 5; ++it) tokB[it * 320 + t] = clik[b * (HN * LN) + it * 320 + t];
    __syncthreads();

    {   // stage A once: 1280 chunks of 16B, 4 per thread; src pre-swizzled, dest linear
        #pragma unroll
        for (int it = 0; it < 4; ++it) {
            int cid = it * 320 + t, row = cid / 40, ch = cid % 40;
            int csrc = (ch & ~7) | ((ch & 7) ^ (row & 7));
            *(int4*)((char*)Abuf + row * 640 + ch * 16) =
                *(const int4*)((const char*)tab + (size_t)tokA[row] * (DP * 2) + csrc * 16);
        }
    }
    __syncthreads();    // the ONLY barrier; waves free-run from here

    const int m15 = lane & 15;
    const int g4  = lane >> 4;

    // pooling constants (R5-proven factorization)
    const float C1   = 10.0f * LOG2E;
    const float C2   = -50.0f * LOG2E;
    const float AK19 = 849.3218002880191f;  // sqrt(LOG2E / (2*0.001^2))
    static const float CkT[10] = {          // e^{-m^2/2}; unrolled k folds these to immediates
        1.0f, 0.6065306597126334f, 0.1353352832366127f, 0.011108996538242306f,
        3.3546262790251185e-4f, 3.7266531720786709e-6f, 1.5229979744712628e-8f,
        2.2897348456191135e-11f, 1.2664165549094176e-14f, 2.576757109154981e-18f };

    float* sb = &simbuf[w][0];
    const float* sp0 = sb + (lane >> 2) * 33 + (lane & 3) * 8;
    float res = 0.f;

    #pragma unroll 1
    for (int hh = 0; hh < 10; ++hh) {
        const int h = w * 10 + hh;
        const char* bb0 = (const char*)tab + (size_t)tokB[h * LN + m15]      * (DP * 2) + g4 * 16;
        const char* bb1 = (const char*)tab + (size_t)tokB[h * LN + 16 + m15] * (DP * 2) + g4 * 16;

        f32x4 a00 = {0.f,0.f,0.f,0.f}, a01 = a00, a10 = a00, a11 = a00;
        bf16x8 b0 = *(const bf16x8*)bb0;
        bf16x8 b1 = *(const bf16x8*)bb1;

        #pragma unroll
        for (int ss = 0; ss < 10; ++ss) {
            bf16x8 b0c = b0, b1c = b1;
            if (ss < 9) {                         // prefetch next K-slice's B frags
                b0 = *(const bf16x8*)(bb0 + (ss + 1) * 64);
                b1 = *(const bf16x8*)(bb1 + (ss + 1) * 64);
            }
            bf16x8 af0 = ldA(Abuf, m15,      ss * 4 + g4);
            bf16x8 af1 = ldA(Abuf, 16 + m15, ss * 4 + g4);
            a00 = __builtin_amdgcn_mfma_f32_16x16x32_bf16(af0, b0c, a00, 0, 0, 0);
            a01 = __builtin_amdgcn_mfma_f32_16x16x32_bf16(af0, b1c, a01, 0, 0, 0);
            a10 = __builtin_amdgcn_mfma_f32_16x16x32_bf16(af1, b0c, a10, 0, 0, 0);
            a11 = __builtin_amdgcn_mfma_f32_16x16x32_bf16(af1, b1c, a11, 0, 0, 0);
        }

        // pool the two 16x32 tiles for this h (wave-private, R11-proven mapping)
        const float* wrow = ltr_w + h * KNN;
        #pragma unroll
        for (int at = 0; at < 2; ++at) {
            f32x4 t0 = at ? a10 : a00;
            f32x4 t1 = at ? a11 : a01;
            #pragma unroll
            for (int r = 0; r < 4; ++r) {
                sb[(g4 * 4 + r) * 33 + m15]      = t0[r];   // C/D: col=lane&15, row=g4*4+r
                sb[(g4 * 4 + r) * 33 + 16 + m15] = t1[r];
            }
            // wave-internal LDS ordering (lgkmcnt) makes writes visible below

            float Q[KNN];
            #pragma unroll
            for (int k = 0; k < KNN; ++k) Q[k] = 0.f;
            #pragma unroll
            for (int e = 0; e < 8; ++e) {
                float s  = sp0[e];
                float cs = C1 * s;
                float tt = FEXP2(cs);
                float uu = FEXP2(-cs);
                float e0 = FEXP2(C2 * (s * s));
                Q[9] += e0;
                float ap = e0, am = e0;
                ap *= tt;  Q[10] += ap;   am *= uu;  Q[8] += am;
                ap *= tt;  Q[11] += ap;   am *= uu;  Q[7] += am;
                ap *= tt;  Q[12] += ap;   am *= uu;  Q[6] += am;
                ap *= tt;  Q[13] += ap;   am *= uu;  Q[5] += am;
                ap *= tt;  Q[14] += ap;   am *= uu;  Q[4] += am;
                ap *= tt;  Q[15] += ap;   am *= uu;  Q[3] += am;
                ap *= tt;  Q[16] += ap;   am *= uu;  Q[2] += am;
                ap *= tt;  Q[17] += ap;   am *= uu;  Q[1] += am;
                ap *= tt;  Q[18] += ap;   am *= uu;  Q[0] += am;
                float d = fmaf(s, AK19, -AK19);
                Q[19] += FEXP2(-(d * d));
            }
            #pragma unroll
            for (int k = 0; k < KNN; ++k) {       // 4-lane row reduce (DPP quad perms)
                Q[k] += __shfl_xor(Q[k], 1);
                Q[k] += __shfl_xor(Q[k], 2);
            }
            float rs = 0.f;
            #pragma unroll
            for (int k = 0; k < KNN - 1; ++k) {
                int ai = (k < 9) ? (9 - k) : (k - 9);
                rs += wrow[k] * FLOG2(fmaxf(Q[k] * CkT[ai], 1e-10f));
            }
            rs += wrow[KNN - 1] * FLOG2(fmaxf(Q[KNN - 1], 1e-10f));
            res += rs;
        }
    }

    // each row counted by 4 lanes -> x0.25; log2 -> ln
    res *= 0.25f * LN2F;
    #pragma unroll
    for (int off = 32; off; off >>= 1) res += __shfl_xor(res, off);
    if (lane == 0) atomicAdd(&score[b * CN + c], res);   // 5 waves -> same cell, atomic
}

// ---------------- kernel 3: log_softmax over C (ltr_b cancels) ----------------
__global__ __launch_bounds__(128) void knrm_final(const float* __restrict__ score,
                                                  float* __restrict__ out) {
    int b = threadIdx.x;
    if (b < BN) {
        float s[CN];
        float m = -1e30f;
        #pragma unroll
        for (int c = 0; c < CN; ++c) { s[c] = score[b * CN + c]; m = fmaxf(m, s[c]); }
        float sum = 0.f;
        #pragma unroll
        for (int c = 0; c < CN; ++c) sum += FEXP2((s[c] - m) * LOG2E);
        float lse = m + FLOG2(sum) * LN2F;
        #pragma unroll
        for (int c = 0; c < CN; ++c) out[b * CN + c] = s[c] - lse;
    }
}

extern "C" void kernel_launch(void* const* d_in, const int* in_sizes, int n_in,
                              void* d_out, int out_size, void* d_ws, size_t ws_size,
                              hipStream_t stream) {
    const int*   cand  = (const int*)d_in[0];   // [B,C,L]
    const int*   clik  = (const int*)d_in[1];   // [B,H,L]
    const float* emb   = (const float*)d_in[2]; // [VOCAB,D]
    const float* ltr_w = (const float*)d_in[3]; // [1,H*KN]
    float* out = (float*)d_out;

    const size_t TAB_B = (size_t)VOCABN * DP * 2;   // 32,000,000

    ushort* tab  = (ushort*)d_ws;
    float*  scre = (float*)((char*)d_ws + TAB_B);

    hipMemsetAsync(scre, 0, BN * CN * sizeof(float), stream);
    knorm_embed2<<<VOCABN / 4, 256, 0, stream>>>(emb, tab);
    knrm_fused4<<<BN * CN, 320, 0, stream>>>(cand, clik, tab, ltr_w, scre);
    knrm_final<<<1, 128, 0, stream>>>(scre, out);
}

// Round 13
// 136.310 us; speedup vs baseline: 1.8884x; 1.8884x over previous
//
#include <hip/hip_runtime.h>
#include <hip/hip_bf16.h>

#define VOCABN 50000
#define BN 128
#define CN 5
#define HN 50
#define LN 32
#define DN 300
#define DP 320     // padded K
#define KNN 20

typedef __bf16    bf16x8 __attribute__((ext_vector_type(8)));
typedef float     f32x4  __attribute__((ext_vector_type(4)));
typedef ushort    u16x8  __attribute__((ext_vector_type(8)));

#if __has_builtin(__builtin_amdgcn_exp2f)
#define FEXP2 __builtin_amdgcn_exp2f
#else
#define FEXP2 exp2f
#endif
#if __has_builtin(__builtin_amdgcn_logf)
#define FLOG2 __builtin_amdgcn_logf
#else
#define FLOG2 log2f
#endif

#define LOG2E 1.4426950408889634f
#define LN2F  0.6931471805599453f

// ---------------- kernel 1: normalize vocab -> bf16 table, wave-per-row (R11-proven) ----------------
__global__ __launch_bounds__(256) void knorm_embed2(const float* __restrict__ emb,
                                                    ushort* __restrict__ tabo) {
    const int t    = threadIdx.x;
    const int lane = t & 63;
    const int w    = t >> 6;
    const int v    = blockIdx.x * 4 + w;          // grid 12500 x 4 waves
    const float* row = emb + (size_t)v * DN;
    const float4* r4 = (const float4*)row;

    float4 x = r4[lane];
    float ss = x.x * x.x + x.y * x.y + x.z * x.z + x.w * x.w;
    if (lane < 11) {
        float4 y = r4[64 + lane];
        ss += y.x * y.x + y.y * y.y + y.z * y.z + y.w * y.w;
    }
    #pragma unroll
    for (int off = 32; off; off >>= 1) ss += __shfl_xor(ss, off);
    const float scale = 1.0f / fmaxf(sqrtf(ss), 1e-8f);

    if (lane < 40) {
        u16x8 u;
        #pragma unroll
        for (int j = 0; j < 8; ++j) {
            int e = lane * 8 + j;
            float f = (e < DN) ? row[e] * scale : 0.f;
            __hip_bfloat16 h = __float2bfloat16(f);
            u[j] = *(ushort*)&h;
        }
        *(u16x8*)(tabo + (size_t)v * DP + lane * 8) = u;
    }
}

// Slice buffers: [row][64 ushorts] = 128B rows; 16B chunks XOR-swizzled (R6-proven).
__device__ inline bf16x8 ldfrag(const ushort* buf, int row, int chunk) {
    int pos = chunk ^ (row & 7);
    return *(const bf16x8*)((const char*)buf + row * 128 + pos * 16);
}

// ---------------- kernel 2: fused GEMM + pooling, small blocks (b x 25 h-pairs) ----------------
// 3200 blocks, 320 threads, ~29 KB LDS, acc[2][4]=32 regs -> ~5 blocks/CU.
// GEMM: R6-proven skeleton (5 K-slices of 64, XOR-swizzled A+B, 2 barriers/slice).
// Pool: fused after one barrier; simbuf aliases dead Abuf; R5 factorization.
__global__ __launch_bounds__(320, 4) void knrm_fused5(const int* __restrict__ cand,
                                                      const int* __restrict__ clik,
                                                      const ushort* __restrict__ tab,
                                                      const float* __restrict__ ltr_w,
                                                      float* __restrict__ score) {
    __shared__ __align__(16) char   smem[160 * 128];   // 20 KB: Abuf (GEMM) / simbuf (pool)
    __shared__ __align__(16) ushort Bbuf[64 * 64];     // 8 KB
    __shared__ int tokA[160];
    __shared__ int tokB[64];

    ushort* Abuf = (ushort*)smem;

    const int t    = threadIdx.x;
    const int lane = t & 63;
    const int w    = t >> 6;          // wave 0..4 == candidate c
    // T1: bijective XCD swizzle (grid 3200 = 8 x 400); 25 same-b blocks land co-XCD
    const int bid  = (blockIdx.x & 7) * 400 + (blockIdx.x >> 3);
    const int b    = bid / 25;
    const int hg   = bid % 25;        // h-pair group: h = hg*2, hg*2+1
    const int h0   = hg * 2;

    if (t < 160)      tokA[t] = cand[b * (CN * LN) + t];
    else if (t < 224) tokB[t - 160] = clik[b * (HN * LN) + h0 * LN + (t - 160)];
    __syncthreads();

    const int m15 = lane & 15;
    const int g4  = lane >> 4;

    f32x4 acc[2][4];
    #pragma unroll
    for (int at = 0; at < 2; ++at)
        #pragma unroll
        for (int jg = 0; jg < 4; ++jg)
            acc[at][jg] = (f32x4){0.f, 0.f, 0.f, 0.f};

    #pragma unroll 1
    for (int ss = 0; ss < 5; ++ss) {
        __syncthreads();                          // buffers free
        {   // stage A: 1280 chunks, 4/thread; B: 512 chunks, 2/thread (t<256)
            int4 rga[4], rgb[2];
            #pragma unroll
            for (int it = 0; it < 4; ++it) {
                int cid = it * 320 + t, row = cid >> 3, c = cid & 7;
                rga[it] = *(const int4*)((const char*)tab +
                    (size_t)tokA[row] * (DP * 2) + ss * 128 + ((c ^ (row & 7)) << 4));
            }
            if (t < 256) {
                #pragma unroll
                for (int it = 0; it < 2; ++it) {
                    int cid = it * 256 + t, row = cid >> 3, c = cid & 7;
                    rgb[it] = *(const int4*)((const char*)tab +
                        (size_t)tokB[row] * (DP * 2) + ss * 128 + ((c ^ (row & 7)) << 4));
                }
            }
            #pragma unroll
            for (int it = 0; it < 4; ++it) {
                int cid = it * 320 + t, row = cid >> 3, c = cid & 7;
                *(int4*)((char*)Abuf + row * 128 + c * 16) = rga[it];
            }
            if (t < 256) {
                #pragma unroll
                for (int it = 0; it < 2; ++it) {
                    int cid = it * 256 + t, row = cid >> 3, c = cid & 7;
                    *(int4*)((char*)Bbuf + row * 128 + c * 16) = rgb[it];
                }
            }
        }
        __syncthreads();                          // slice ready
        #pragma unroll
        for (int kc = 0; kc < 2; ++kc) {
            bf16x8 af0 = ldfrag(Abuf, w * 32 + m15,      kc * 4 + g4);
            bf16x8 af1 = ldfrag(Abuf, w * 32 + 16 + m15, kc * 4 + g4);
            #pragma unroll
            for (int jg = 0; jg < 4; ++jg) {
                bf16x8 bf = ldfrag(Bbuf, jg * 16 + m15, kc * 4 + g4);
                acc[0][jg] = __builtin_amdgcn_mfma_f32_16x16x32_bf16(af0, bf, acc[0][jg], 0, 0, 0);
                acc[1][jg] = __builtin_amdgcn_mfma_f32_16x16x32_bf16(af1, bf, acc[1][jg], 0, 0, 0);
            }
        }
    }
    __syncthreads();    // all Abuf/Bbuf reads done -> smem safe to reuse as simbuf

    // ---- fused pooling (R5 factorization, R11-proven mapping), wave-private ----
    const float C1   = 10.0f * LOG2E;
    const float C2   = -50.0f * LOG2E;
    const float AK19 = 849.3218002880191f;  // sqrt(LOG2E / (2*0.001^2))
    static const float CkT[10] = {          // e^{-m^2/2}; unrolled k folds to immediates
        1.0f, 0.6065306597126334f, 0.1353352832366127f, 0.011108996538242306f,
        3.3546262790251185e-4f, 3.7266531720786709e-6f, 1.5229979744712628e-8f,
        2.2897348456191135e-11f, 1.2664165549094176e-14f, 2.576757109154981e-18f };

    float* sb = (float*)smem + w * (16 * 33);     // [16][33] f32, wave-private
    const float* sp0 = sb + (lane >> 2) * 33 + (lane & 3) * 8;
    float res = 0.f;

    #pragma unroll
    for (int hl = 0; hl < 2; ++hl) {
        const float* wrow = ltr_w + (h0 + hl) * KNN;
        #pragma unroll
        for (int at = 0; at < 2; ++at) {
            // dump tile: C/D col=lane&15, row=(lane>>4)*4+r [m89-verified]
            #pragma unroll
            for (int r = 0; r < 4; ++r) {
                sb[(g4 * 4 + r) * 33 + m15]      = acc[at][hl * 2][r];
                sb[(g4 * 4 + r) * 33 + 16 + m15] = acc[at][hl * 2 + 1][r];
            }
            // wave-internal lgkmcnt ordering makes writes visible below

            float Q[KNN];
            #pragma unroll
            for (int k = 0; k < KNN; ++k) Q[k] = 0.f;
            #pragma unroll
            for (int e = 0; e < 8; ++e) {
                float s  = sp0[e];
                float cs = C1 * s;
                float tt = FEXP2(cs);
                float uu = FEXP2(-cs);
                float e0 = FEXP2(C2 * (s * s));
                Q[9] += e0;
                float ap = e0, am = e0;
                ap *= tt;  Q[10] += ap;   am *= uu;  Q[8] += am;
                ap *= tt;  Q[11] += ap;   am *= uu;  Q[7] += am;
                ap *= tt;  Q[12] += ap;   am *= uu;  Q[6] += am;
                ap *= tt;  Q[13] += ap;   am *= uu;  Q[5] += am;
                ap *= tt;  Q[14] += ap;   am *= uu;  Q[4] += am;
                ap *= tt;  Q[15] += ap;   am *= uu;  Q[3] += am;
                ap *= tt;  Q[16] += ap;   am *= uu;  Q[2] += am;
                ap *= tt;  Q[17] += ap;   am *= uu;  Q[1] += am;
                ap *= tt;  Q[18] += ap;   am *= uu;  Q[0] += am;
                float d = fmaf(s, AK19, -AK19);   // (s-1)*AK19
                Q[19] += FEXP2(-(d * d));         // sharp sigma=0.001 kernel
            }
            #pragma unroll
            for (int k = 0; k < KNN; ++k) {       // 4-lane row reduce (DPP quad perms)
                Q[k] += __shfl_xor(Q[k], 1);
                Q[k] += __shfl_xor(Q[k], 2);
            }
            float rs = 0.f;
            #pragma unroll
            for (int k = 0; k < KNN - 1; ++k) {
                int ai = (k < 9) ? (9 - k) : (k - 9);
                rs += wrow[k] * FLOG2(fmaxf(Q[k] * CkT[ai], 1e-10f));
            }
            rs += wrow[KNN - 1] * FLOG2(fmaxf(Q[KNN - 1], 1e-10f));
            res += rs;
        }
    }

    // each row counted by 4 lanes -> x0.25; log2 -> ln
    res *= 0.25f * LN2F;
    #pragma unroll
    for (int off = 32; off; off >>= 1) res += __shfl_xor(res, off);
    if (lane == 0) atomicAdd(&score[b * CN + w], res);
}

// ---------------- kernel 3: log_softmax over C (ltr_b cancels) ----------------
__global__ __launch_bounds__(128) void knrm_final(const float* __restrict__ score,
                                                  float* __restrict__ out) {
    int b = threadIdx.x;
    if (b < BN) {
        float s[CN];
        float m = -1e30f;
        #pragma unroll
        for (int c = 0; c < CN; ++c) { s[c] = score[b * CN + c]; m = fmaxf(m, s[c]); }
        float sum = 0.f;
        #pragma unroll
        for (int c = 0; c < CN; ++c) sum += FEXP2((s[c] - m) * LOG2E);
        float lse = m + FLOG2(sum) * LN2F;
        #pragma unroll
        for (int c = 0; c < CN; ++c) out[b * CN + c] = s[c] - lse;
    }
}

extern "C" void kernel_launch(void* const* d_in, const int* in_sizes, int n_in,
                              void* d_out, int out_size, void* d_ws, size_t ws_size,
                              hipStream_t stream) {
    const int*   cand  = (const int*)d_in[0];   // [B,C,L]
    const int*   clik  = (const int*)d_in[1];   // [B,H,L]
    const float* emb   = (const float*)d_in[2]; // [VOCAB,D]
    const float* ltr_w = (const float*)d_in[3]; // [1,H*KN]
    float* out = (float*)d_out;

    const size_t TAB_B = (size_t)VOCABN * DP * 2;   // 32,000,000

    ushort* tab  = (ushort*)d_ws;
    float*  scre = (float*)((char*)d_ws + TAB_B);

    hipMemsetAsync(scre, 0, BN * CN * sizeof(float), stream);
    knorm_embed2<<<VOCABN / 4, 256, 0, stream>>>(emb, tab);
    knrm_fused5<<<BN * 25, 320, 0, stream>>>(cand, clik, tab, ltr_w, scre);
    knrm_final<<<1, 128, 0, stream>>>(scre, out);
}

// Round 14
// 131.793 us; speedup vs baseline: 1.9531x; 1.0343x over previous
//
#include <hip/hip_runtime.h>
#include <hip/hip_bf16.h>

#define VOCABN 50000
#define BN 128
#define CN 5
#define HN 50
#define LN 32
#define DN 300
#define DP 320     // padded K
#define KNN 20

typedef __bf16    bf16x8 __attribute__((ext_vector_type(8)));
typedef float     f32x4  __attribute__((ext_vector_type(4)));
typedef float     f32x2  __attribute__((ext_vector_type(2)));
typedef ushort    u16x8  __attribute__((ext_vector_type(8)));

#if __has_builtin(__builtin_amdgcn_exp2f)
#define FEXP2 __builtin_amdgcn_exp2f
#else
#define FEXP2 exp2f
#endif
#if __has_builtin(__builtin_amdgcn_logf)
#define FLOG2 __builtin_amdgcn_logf
#else
#define FLOG2 log2f
#endif

#define LOG2E 1.4426950408889634f
#define LN2F  0.6931471805599453f

// ---------------- kernel 1: normalize vocab -> bf16 table, wave-per-row (R11-proven) ----------------
__global__ __launch_bounds__(256) void knorm_embed2(const float* __restrict__ emb,
                                                    ushort* __restrict__ tabo) {
    const int t    = threadIdx.x;
    const int lane = t & 63;
    const int w    = t >> 6;
    const int v    = blockIdx.x * 4 + w;          // grid 12500 x 4 waves
    const float* row = emb + (size_t)v * DN;
    const float4* r4 = (const float4*)row;

    float4 x = r4[lane];
    float ss = x.x * x.x + x.y * x.y + x.z * x.z + x.w * x.w;
    if (lane < 11) {
        float4 y = r4[64 + lane];
        ss += y.x * y.x + y.y * y.y + y.z * y.z + y.w * y.w;
    }
    #pragma unroll
    for (int off = 32; off; off >>= 1) ss += __shfl_xor(ss, off);
    const float scale = 1.0f / fmaxf(sqrtf(ss), 1e-8f);

    if (lane < 40) {
        u16x8 u;
        #pragma unroll
        for (int j = 0; j < 8; ++j) {
            int e = lane * 8 + j;
            float f = (e < DN) ? row[e] * scale : 0.f;
            __hip_bfloat16 h = __float2bfloat16(f);
            u[j] = *(ushort*)&h;
        }
        *(u16x8*)(tabo + (size_t)v * DP + lane * 8) = u;
    }
}

// Slice buffers: [row][64 ushorts] = 128B rows; 16B chunks XOR-swizzled (R6-proven).
__device__ inline bf16x8 ldfrag(const ushort* buf, int row, int chunk) {
    int pos = chunk ^ (row & 7);
    return *(const bf16x8*)((const char*)buf + row * 128 + pos * 16);
}

// ---------------- kernel 2: fused GEMM + pooling, small blocks (R13-proven skeleton) ----------------
// 3200 blocks (b x 25 h-pairs), 320 threads, ~29 KB LDS, acc[2][4]=32 regs.
// R14 deltas: packed-f32 pool chain (v_pk_*), hoisted staging pointers.
__global__ __launch_bounds__(320, 4) void knrm_fused5(const int* __restrict__ cand,
                                                      const int* __restrict__ clik,
                                                      const ushort* __restrict__ tab,
                                                      const float* __restrict__ ltr_w,
                                                      float* __restrict__ score) {
    __shared__ __align__(16) char   smem[160 * 128];   // 20 KB: Abuf (GEMM) / simbuf (pool)
    __shared__ __align__(16) ushort Bbuf[64 * 64];     // 8 KB
    __shared__ int tokA[160];
    __shared__ int tokB[64];

    ushort* Abuf = (ushort*)smem;

    const int t    = threadIdx.x;
    const int lane = t & 63;
    const int w    = t >> 6;          // wave 0..4 == candidate c
    // T1: bijective XCD swizzle (grid 3200 = 8 x 400); 25 same-b blocks land co-XCD
    const int bid  = (blockIdx.x & 7) * 400 + (blockIdx.x >> 3);
    const int b    = bid / 25;
    const int hg   = bid % 25;        // h-pair group: h = hg*2, hg*2+1
    const int h0   = hg * 2;

    if (t < 160)      tokA[t] = cand[b * (CN * LN) + t];
    else if (t < 224) tokB[t - 160] = clik[b * (HN * LN) + h0 * LN + (t - 160)];
    __syncthreads();

    const int m15 = lane & 15;
    const int g4  = lane >> 4;

    // hoisted staging geometry: per-thread src/dst pointers, src walks +128B per slice
    const char* srcA[4]; char* dstA[4];
    #pragma unroll
    for (int it = 0; it < 4; ++it) {
        int cid = it * 320 + t, row = cid >> 3, c = cid & 7;
        srcA[it] = (const char*)tab + (size_t)tokA[row] * (DP * 2) + ((c ^ (row & 7)) << 4);
        dstA[it] = (char*)Abuf + row * 128 + c * 16;
    }
    const char* srcB[2]; char* dstB[2];
    {
        int tb = (t < 256) ? t : (t - 64);        // waves 0-3 stage B; wave 4 aliases (unused)
        #pragma unroll
        for (int it = 0; it < 2; ++it) {
            int cid = it * 256 + tb, row = cid >> 3, c = cid & 7;
            srcB[it] = (const char*)tab + (size_t)tokB[row] * (DP * 2) + ((c ^ (row & 7)) << 4);
            dstB[it] = (char*)Bbuf + row * 128 + c * 16;
        }
    }

    f32x4 acc[2][4];
    #pragma unroll
    for (int at = 0; at < 2; ++at)
        #pragma unroll
        for (int jg = 0; jg < 4; ++jg)
            acc[at][jg] = (f32x4){0.f, 0.f, 0.f, 0.f};

    #pragma unroll 1
    for (int ss = 0; ss < 5; ++ss) {
        const int so = ss * 128;
        __syncthreads();                          // buffers free
        {
            int4 rga[4], rgb[2];
            #pragma unroll
            for (int it = 0; it < 4; ++it) rga[it] = *(const int4*)(srcA[it] + so);
            if (t < 256) {
                #pragma unroll
                for (int it = 0; it < 2; ++it) rgb[it] = *(const int4*)(srcB[it] + so);
            }
            #pragma unroll
            for (int it = 0; it < 4; ++it) *(int4*)dstA[it] = rga[it];
            if (t < 256) {
                #pragma unroll
                for (int it = 0; it < 2; ++it) *(int4*)dstB[it] = rgb[it];
            }
        }
        __syncthreads();                          // slice ready
        #pragma unroll
        for (int kc = 0; kc < 2; ++kc) {
            bf16x8 af0 = ldfrag(Abuf, w * 32 + m15,      kc * 4 + g4);
            bf16x8 af1 = ldfrag(Abuf, w * 32 + 16 + m15, kc * 4 + g4);
            #pragma unroll
            for (int jg = 0; jg < 4; ++jg) {
                bf16x8 bf = ldfrag(Bbuf, jg * 16 + m15, kc * 4 + g4);
                acc[0][jg] = __builtin_amdgcn_mfma_f32_16x16x32_bf16(af0, bf, acc[0][jg], 0, 0, 0);
                acc[1][jg] = __builtin_amdgcn_mfma_f32_16x16x32_bf16(af1, bf, acc[1][jg], 0, 0, 0);
            }
        }
    }
    __syncthreads();    // all Abuf/Bbuf reads done -> smem safe to reuse as simbuf

    // ---- fused pooling: R5 factorization, packed-f32 chains ----
    const float C1   = 10.0f * LOG2E;
    const float C2   = -50.0f * LOG2E;
    const float AK19 = 849.3218002880191f;  // sqrt(LOG2E / (2*0.001^2))
    static const float CkT[10] = {          // e^{-m^2/2}; unrolled j folds to immediates
        1.0f, 0.6065306597126334f, 0.1353352832366127f, 0.011108996538242306f,
        3.3546262790251185e-4f, 3.7266531720786709e-6f, 1.5229979744712628e-8f,
        2.2897348456191135e-11f, 1.2664165549094176e-14f, 2.576757109154981e-18f };

    float* sb = (float*)smem + w * (16 * 33);     // [16][33] f32, wave-private
    const float* sp0 = sb + (lane >> 2) * 33 + (lane & 3) * 8;
    float res = 0.f;

    #pragma unroll
    for (int hl = 0; hl < 2; ++hl) {
        const float* wrow = ltr_w + (h0 + hl) * KNN;
        #pragma unroll
        for (int at = 0; at < 2; ++at) {
            // dump tile: C/D col=lane&15, row=(lane>>4)*4+r [m89-verified]
            #pragma unroll
            for (int r = 0; r < 4; ++r) {
                sb[(g4 * 4 + r) * 33 + m15]      = acc[at][hl * 2][r];
                sb[(g4 * 4 + r) * 33 + 16 + m15] = acc[at][hl * 2 + 1][r];
            }
            // wave-internal lgkmcnt ordering makes writes visible below

            f32x2 Qp[9];                          // Qp[j-1] = {Q[9+j], Q[9-j]}
            #pragma unroll
            for (int j = 0; j < 9; ++j) Qp[j] = (f32x2){0.f, 0.f};
            float Q9 = 0.f, Q19 = 0.f;

            #pragma unroll
            for (int e = 0; e < 8; ++e) {
                float s  = sp0[e];
                float cs = C1 * s;
                float tt = FEXP2(cs);
                float uu = FEXP2(-cs);
                float e0 = FEXP2(C2 * (s * s));
                Q9 += e0;
                f32x2 tu = {tt, uu};
                f32x2 pm = {e0, e0};
                #pragma unroll
                for (int j = 0; j < 9; ++j) { pm *= tu; Qp[j] += pm; }  // v_pk_mul/add
                float d = fmaf(s, AK19, -AK19);   // (s-1)*AK19
                Q19 += FEXP2(-(d * d));           // sharp sigma=0.001 kernel
            }
            // 4-lane row reduce (DPP quad perms), per component
            #pragma unroll
            for (int j = 0; j < 9; ++j) {
                Qp[j].x += __shfl_xor(Qp[j].x, 1); Qp[j].x += __shfl_xor(Qp[j].x, 2);
                Qp[j].y += __shfl_xor(Qp[j].y, 1); Qp[j].y += __shfl_xor(Qp[j].y, 2);
            }
            Q9  += __shfl_xor(Q9, 1);  Q9  += __shfl_xor(Q9, 2);
            Q19 += __shfl_xor(Q19, 1); Q19 += __shfl_xor(Q19, 2);

            // weighted log-sum; j unrolled -> CkT immediates. k=9+j (+), k=9-j (-)
            float rs = wrow[9] * FLOG2(fmaxf(Q9, 1e-10f));
            #pragma unroll
            for (int j = 1; j <= 9; ++j) {
                rs += wrow[9 + j] * FLOG2(fmaxf(Qp[j - 1].x * CkT[j], 1e-10f));
                rs += wrow[9 - j] * FLOG2(fmaxf(Qp[j - 1].y * CkT[j], 1e-10f));
            }
            rs += wrow[19] * FLOG2(fmaxf(Q19, 1e-10f));
            res += rs;
        }
    }

    // each row counted by 4 lanes -> x0.25; log2 -> ln
    res *= 0.25f * LN2F;
    #pragma unroll
    for (int off = 32; off; off >>= 1) res += __shfl_xor(res, off);
    if (lane == 0) atomicAdd(&score[b * CN + w], res);
}

// ---------------- kernel 3: log_softmax over C (ltr_b cancels) ----------------
__global__ __launch_bounds__(128) void knrm_final(const float* __restrict__ score,
                                                  float* __restrict__ out) {
    int b = threadIdx.x;
    if (b < BN) {
        float s[CN];
        float m = -1e30f;
        #pragma unroll
        for (int c = 0; c < CN; ++c) { s[c] = score[b * CN + c]; m = fmaxf(m, s[c]); }
        float sum = 0.f;
        #pragma unroll
        for (int c = 0; c < CN; ++c) sum += FEXP2((s[c] - m) * LOG2E);
        float lse = m + FLOG2(sum) * LN2F;
        #pragma unroll
        for (int c = 0; c < CN; ++c) out[b * CN + c] = s[c] - lse;
    }
}

extern "C" void kernel_launch(void* const* d_in, const int* in_sizes, int n_in,
                              void* d_out, int out_size, void* d_ws, size_t ws_size,
                              hipStream_t stream) {
    const int*   cand  = (const int*)d_in[0];   // [B,C,L]
    const int*   clik  = (const int*)d_in[1];   // [B,H,L]
    const float* emb   = (const float*)d_in[2]; // [VOCAB,D]
    const float* ltr_w = (const float*)d_in[3]; // [1,H*KN]
    float* out = (float*)d_out;

    const size_t TAB_B = (size_t)VOCABN * DP * 2;   // 32,000,000

    ushort* tab  = (ushort*)d_ws;
    float*  scre = (float*)((char*)d_ws + TAB_B);

    hipMemsetAsync(scre, 0, BN * CN * sizeof(float), stream);
    knorm_embed2<<<VOCABN / 4, 256, 0, stream>>>(emb, tab);
    knrm_fused5<<<BN * 25, 320, 0, stream>>>(cand, clik, tab, ltr_w, scre);
    knrm_final<<<1, 128, 0, stream>>>(scre, out);
}